// Round 5
// baseline (389.563 us; speedup 1.0000x reference)
//
#include <hip/hip_runtime.h>
#include <hip/hip_bf16.h>

#define EMB 256
#define HD 128

typedef __bf16 bf16_t;
typedef __attribute__((ext_vector_type(8))) __bf16 bf16x8;
typedef __attribute__((ext_vector_type(4))) __bf16 bf16x4;
typedef __attribute__((ext_vector_type(4))) float floatx4;

// ---------- helpers ----------
__device__ __forceinline__ int eidx(const int* __restrict__ p, int is64, long long k){
  return is64 ? p[2*k] : p[(int)k];
}
// async global->LDS, 16B per lane; LDS base must be WAVE-UNIFORM, lands at base + lane*16
__device__ __forceinline__ void async_load16(const void* g, void* l){
  __builtin_amdgcn_global_load_lds(
      (const __attribute__((address_space(1))) unsigned int*)g,
      (__attribute__((address_space(3))) unsigned int*)l,
      16, 0, 0);
}
__device__ __forceinline__ float4 cvt4(bf16x4 v){
  return make_float4((float)v.x, (float)v.y, (float)v.z, (float)v.w);
}

// ---------- dtype detect ----------
__global__ void detect_kernel(const int* __restrict__ ei, int* __restrict__ flag){
  int z = (ei[1]==0) + (ei[3]==0) + (ei[5]==0) + (ei[7]==0);
  *flag = (z == 4) ? 1 : 0;
}

// ---------- x -> bf16 ----------
__global__ void cvt_x_kernel(const float* __restrict__ x, bf16_t* __restrict__ xb, int n4){
  int t = blockIdx.x*blockDim.x + threadIdx.x;
  if (t >= n4) return;
  const float4 v = *(const float4*)(x + (size_t)t*4);
  bf16x4 o = { (bf16_t)v.x, (bf16_t)v.y, (bf16_t)v.z, (bf16_t)v.w };
  *(bf16x4*)(xb + (size_t)t*4) = o;
}

// ---------- fold W1 into Wkqv; emit TRANSPOSED bf16 WcombT[768][256] + fp32 bcomb[768] ----------
__global__ void prep_weights(const float* __restrict__ Wkqv, const float* __restrict__ bkqv,
                             const float* __restrict__ W1,
                             bf16_t* __restrict__ WcombT, float* __restrict__ bcomb){
  int n = blockIdx.x * blockDim.x + threadIdx.x;   // 0..767 (output col)
  int c = blockIdx.y;                              // 0..256 (k index; 256 = bias)
  if (n >= 768) return;
  const float rs = rsqrtf(128.0f);
  bool isBias = (c == 256);
  const float* arow = isBias ? bkqv : (Wkqv + (size_t)c*768);
  float val;
  if (n < 512){
    bool isQ = (n < 256);
    int nn = isQ ? n : (n - 256);
    int h = nn >> 7, d = nn & 127;
    int srcoff = isQ ? (h*128) : (256 + h*128);
    int w1off  = isQ ? 128 : 0;
    float s = 0.f;
    for (int t = 0; t < 128; ++t)
      s = fmaf(arow[srcoff + t], W1[(size_t)(w1off + t)*128 + d], s);
    val = isQ ? s : s * rs;
  } else {
    val = arow[512 + (n - 512)];
  }
  if (isBias) bcomb[n] = val;
  else        WcombT[(size_t)n*256 + c] = (bf16_t)val;
}

// ---------- Wout -> transposed bf16 WoutT[256][256] ----------
__global__ void prep_wout(const float* __restrict__ W, bf16_t* __restrict__ Wt){
  int t = blockIdx.x*blockDim.x + threadIdx.x;  // 65536
  int n = t & 255, c = t >> 8;
  Wt[(size_t)n*256 + c] = (bf16_t)W[(size_t)c*256 + n];
}

// ---------- degree count over the 2*E0 non-self edges (dst side) ----------
__global__ void deg_kernel(const int* __restrict__ ei, const int* __restrict__ flag,
                           int* __restrict__ deg, int E0, int Nn){
  int t = blockIdx.x*blockDim.x + threadIdx.x;
  if (t >= 2*E0) return;
  int is64 = *flag;
  int i = (t < E0) ? eidx(ei,is64,(long long)E0+t) : eidx(ei,is64,t-E0);
  i = min(max(i,0), Nn-1);
  atomicAdd(deg + i, 1);
}

// ---------- exclusive prefix scan of (deg+1) -> off[0..N] (self-loop slot included) ----------
__global__ __launch_bounds__(1024) void scan_kernel(const int* __restrict__ deg,
                                                    int* __restrict__ off, int N){
  __shared__ int wsum[16];
  __shared__ int carry_s;
  int tid = threadIdx.x, lane = tid & 63, w = tid >> 6;
  if (tid == 0) carry_s = 0;
  __syncthreads();
  for (int base = 0; base < N; base += 1024){
    int carry = carry_s;
    int v = (base + tid < N) ? (deg[base + tid] + 1) : 0;
    int incl = v;
    #pragma unroll
    for (int o = 1; o < 64; o <<= 1){
      int t = __shfl_up(incl, o, 64);
      if (lane >= o) incl += t;
    }
    if (lane == 63) wsum[w] = incl;
    __syncthreads();
    if (w == 0 && lane < 16){
      int sv = wsum[lane];
      #pragma unroll
      for (int o = 1; o < 16; o <<= 1){
        int t = __shfl_up(sv, o, 64);
        if (lane >= o) sv += t;
      }
      wsum[lane] = sv;
    }
    __syncthreads();
    int wpref = (w == 0) ? 0 : wsum[w-1];
    if (base + tid < N) off[base + tid] = carry + wpref + incl - v;
    __syncthreads();
    if (tid == 1023) carry_s = carry + wsum[15];
    __syncthreads();
  }
  if (threadIdx.x == 0) off[N] = carry_s;
}

// ---------- scatter source index j into CSR buckets (incl. self-loops) ----------
__global__ void scatter_kernel(const int* __restrict__ ei, const int* __restrict__ flag,
                               const int* __restrict__ off, int* __restrict__ cursor,
                               int* __restrict__ bj, int E0, int Nn){
  int e = blockIdx.x*blockDim.x + threadIdx.x;
  int E = 2*E0 + Nn;
  if (e >= E) return;
  int is64 = *flag;
  int j, i;
  if (e < E0){ j = eidx(ei,is64,e); i = eidx(ei,is64,(long long)E0+e); }
  else if (e < 2*E0){ int t = e - E0; i = eidx(ei,is64,t); j = eidx(ei,is64,(long long)E0+t); }
  else { i = j = e - 2*E0; }
  i = min(max(i,0), Nn-1); j = min(max(j,0), Nn-1);
  int pos = atomicAdd(cursor + i, 1);
  bj[off[i] + pos] = j;
}

// ---------- strip GEMM: C = A[M,256] @ Bt[N,256]^T + epilogue ----------
// One block = 64-row m-strip, FULL K=256 of A staged in LDS once (32 KB,
// global_load_lds w16, fragment-ordered), ONE barrier total. B streams from
// global (L2/L3-resident weights) straight into registers — no per-iter
// barriers at all (the m97 barrier-drain stall is structural; this removes it).
// 4 waves; wave w covers n-tiles n0 = w*64, w*64+256, ... (64x64 acc each).
// MODE 0: C(bf16) = AB + bias[n]
// MODE 1: C(fp32) = relu(AB + (deg[m]+1)*bias[n]) + xres[m*N+n]
template<int MODE, typename OutT>
__global__ __launch_bounds__(256) void strip_gemm(
    const bf16_t* __restrict__ A, const bf16_t* __restrict__ Bt,
    const float* __restrict__ bias, OutT* __restrict__ C,
    int M, int N,
    const int* __restrict__ deg, const float* __restrict__ xres)
{
  __shared__ bf16_t As[64*256];   // 32 KB, frag (mf,kc) at byte (mf*8+kc)*1024
  const int tid = threadIdx.x;
  const int wave = tid >> 6, lane = tid & 63;
  const int m0 = blockIdx.x * 64;
  const int row16 = lane & 15, quad = lane >> 4;

  // stage A-strip: wave w stages m-frag w (16 rows x 256 k = 8 chunks)
  {
    int gm = min(m0 + wave*16 + row16, M-1);
    const bf16_t* gp = A + (size_t)gm*256;
    #pragma unroll
    for (int kc = 0; kc < 8; ++kc)
      async_load16(gp + kc*32 + quad*8, (char*)As + (wave*8+kc)*1024);
  }
  __syncthreads();   // the only barrier

  for (int n0 = wave*64; n0 < N; n0 += 256){
    floatx4 acc[4][4];
    #pragma unroll
    for (int a=0;a<4;++a)
      #pragma unroll
      for (int b=0;b<4;++b) acc[a][b] = (floatx4){0.f,0.f,0.f,0.f};

    #pragma unroll
    for (int kc = 0; kc < 8; ++kc){
      bf16x8 bfr[4], af[4];
      #pragma unroll
      for (int t = 0; t < 4; ++t)   // global B first (long latency)
        bfr[t] = *(const bf16x8*)(Bt + (size_t)(n0 + t*16 + row16)*256 + kc*32 + quad*8);
      #pragma unroll
      for (int t = 0; t < 4; ++t)   // LDS A (short latency)
        af[t] = *(const bf16x8*)((const char*)As + (t*8+kc)*1024 + lane*16);
      #pragma unroll
      for (int mt=0;mt<4;++mt)
        #pragma unroll
        for (int nt=0;nt<4;++nt)
          acc[mt][nt] = __builtin_amdgcn_mfma_f32_16x16x32_bf16(af[mt], bfr[nt], acc[mt][nt], 0,0,0);
    }

    // epilogue: C/D layout col=lane&15, row=quad*4+reg
    #pragma unroll
    for (int mt=0;mt<4;++mt){
      #pragma unroll
      for (int r=0;r<4;++r){
        int m = m0 + mt*16 + quad*4 + r;
        if (m >= M) continue;
        float dg = (MODE==1) ? (float)(deg[m]+1) : 0.f;
        #pragma unroll
        for (int nt=0;nt<4;++nt){
          int n = n0 + nt*16 + row16;
          float v = acc[mt][nt][r];
          if (MODE == 0){
            v += bias[n];
          } else {
            v = fmaxf(v + dg*bias[n], 0.f) + xres[(size_t)m*N + n];
          }
          C[(size_t)m*N + n] = (OutT)v;
        }
      }
    }
  }
}

// ---------- fused attention: score + online softmax + aggregate, one wave per node ----------
__global__ __launch_bounds__(256) void fused_attn_kernel(
    const bf16_t* __restrict__ P, const int* __restrict__ bj, const int* __restrict__ off,
    const float* __restrict__ b1, const float* __restrict__ W2, const float* __restrict__ b2,
    bf16_t* __restrict__ aggb, int Nn)
{
  int i = blockIdx.x * (blockDim.x >> 6) + (threadIdx.x >> 6);
  if (i >= Nn) return;
  int lane = threadIdx.x & 63;
  int h = lane >> 5, d = (lane & 31) * 4;      // head, elem offset within head

  const float4 qv  = cvt4(*(const bf16x4*)(P + (size_t)i*768 + h*128 + d));
  const float4 b1v = *(const float4*)(b1 + d);
  const float4 w2v = *(const float4*)(W2 + d);
  const float b2v  = b2[0];

  float m = -3.0e38f, s = 0.f;
  float4 acc = make_float4(0.f,0.f,0.f,0.f);
  int s0 = off[i], s1 = off[i+1];
  for (int t = s0; t < s1; ++t){
    int j = bj[t];
    const float4 kv = cvt4(*(const bf16x4*)(P + (size_t)j*768 + 256 + h*128 + d));
    const float4 vv = cvt4(*(const bf16x4*)(P + (size_t)j*768 + 512 + h*128 + d));
    float p = fmaxf(qv.x+kv.x+b1v.x, 0.f)*w2v.x
            + fmaxf(qv.y+kv.y+b1v.y, 0.f)*w2v.y
            + fmaxf(qv.z+kv.z+b1v.z, 0.f)*w2v.z
            + fmaxf(qv.w+kv.w+b1v.w, 0.f)*w2v.w;
    // reduce across the 32-lane half-wave (bit5 = head, untouched)
    #pragma unroll
    for (int o = 16; o >= 1; o >>= 1)
      p += __shfl_xor(p, o, 64);
    float a = p + b2v;
    float mn = fmaxf(m, a);
    float sc = __expf(m - mn);
    float e  = __expf(a - mn);
    s = s*sc + e;
    acc.x = fmaf(acc.x, sc, e*vv.x);
    acc.y = fmaf(acc.y, sc, e*vv.y);
    acc.z = fmaf(acc.z, sc, e*vv.z);
    acc.w = fmaf(acc.w, sc, e*vv.w);
    m = mn;
  }
  float inv = 1.f / (s + 1e-16f);
  bf16x4 ob = { (bf16_t)(acc.x*inv), (bf16_t)(acc.y*inv), (bf16_t)(acc.z*inv), (bf16_t)(acc.w*inv) };
  *(bf16x4*)(aggb + (size_t)i*256 + h*128 + d) = ob;
}

// ---------- launch ----------
extern "C" void kernel_launch(void* const* d_in, const int* in_sizes, int n_in,
                              void* d_out, int out_size, void* d_ws, size_t ws_size,
                              hipStream_t stream)
{
  const float* x     = (const float*)d_in[0];
  const int*   ei    = (const int*)d_in[1];
  const float* Wkqv  = (const float*)d_in[2];
  const float* bkqv  = (const float*)d_in[3];
  const float* W1    = (const float*)d_in[4];
  const float* b1    = (const float*)d_in[5];
  const float* W2    = (const float*)d_in[6];
  const float* b2    = (const float*)d_in[7];
  const float* Wout  = (const float*)d_in[8];
  const float* bout  = (const float*)d_in[9];
  float* out = (float*)d_out;

  const int N  = in_sizes[0] / EMB;   // 50000
  const int E0 = in_sizes[1] / 2;     // 100000
  const int E  = 2*E0 + N;            // 250000

  // workspace layout (fp32-word offsets; all 16B-aligned)
  float* base = (float*)d_ws;
  bf16_t* WcombT = (bf16_t*)base;                       // 768*256 bf16 = 98304 w
  float*  bcomb  = base + 98304;                        // 768 w
  bf16_t* WoutT  = (bf16_t*)(base + 98304 + 768);       // 256*256 bf16 = 32768 w
  bf16_t* xb     = (bf16_t*)(base + 131840);            // N*256 bf16
  bf16_t* Pb     = (bf16_t*)(base + 131840 + 6400000);  // N*768 bf16
  bf16_t* aggb   = (bf16_t*)(Pb + (size_t)N*768);       // N*256 bf16
  int* deg       = (int*)(aggb + (size_t)N*256);        // N
  int* cursor    = deg + N;                             // N
  int* flag      = cursor + N;                          // 1
  int* off       = flag + 1;                            // N+1
  int* bj        = off + (N+1);                         // E

  hipMemsetAsync(deg, 0, (size_t)2*N*sizeof(int), stream);  // deg + cursor

  detect_kernel<<<1,1,0,stream>>>(ei, flag);
  cvt_x_kernel<<<((N*EMB/4)+255)/256,256,0,stream>>>(x, xb, N*EMB/4);
  prep_weights<<<dim3(3,257),256,0,stream>>>(Wkqv, bkqv, W1, WcombT, bcomb);
  prep_wout<<<256,256,0,stream>>>(Wout, WoutT);

  deg_kernel<<<(2*E0+255)/256,256,0,stream>>>(ei, flag, deg, E0, N);
  scan_kernel<<<1,1024,0,stream>>>(deg, off, N);
  scatter_kernel<<<(E+255)/256,256,0,stream>>>(ei, flag, off, cursor, bj, E0, N);

  strip_gemm<0, bf16_t><<<(N+63)/64,256,0,stream>>>(xb, WcombT, bcomb, Pb, N, 768, nullptr, nullptr);
  fused_attn_kernel<<<(N+3)/4,256,0,stream>>>(Pb, bj, off, b1, W2, b2, aggb, N);
  strip_gemm<1, float><<<(N+63)/64,256,0,stream>>>(aggb, WoutT, bout, out, N, 256, deg, x);
}

// Round 6
// 344.820 us; speedup vs baseline: 1.1298x; 1.1298x over previous
//
#include <hip/hip_runtime.h>
#include <hip/hip_bf16.h>

#define EMB 256

typedef __bf16 bf16_t;
typedef __attribute__((ext_vector_type(8))) __bf16 bf16x8;
typedef __attribute__((ext_vector_type(4))) __bf16 bf16x4;
typedef __attribute__((ext_vector_type(4))) float floatx4;

// ---------- helpers ----------
__device__ __forceinline__ int eidx(const int* __restrict__ p, int is64, long long k){
  return is64 ? p[2*k] : p[(int)k];
}
// async global->LDS, 16B per lane; LDS base must be WAVE-UNIFORM, lands at base + lane*16
__device__ __forceinline__ void async_load16(const void* g, void* l){
  __builtin_amdgcn_global_load_lds(
      (const __attribute__((address_space(1))) unsigned int*)g,
      (__attribute__((address_space(3))) unsigned int*)l,
      16, 0, 0);
}
__device__ __forceinline__ float4 cvt4(bf16x4 v){
  return make_float4((float)v.x, (float)v.y, (float)v.z, (float)v.w);
}

// ---------- dtype detect ----------
__global__ void detect_kernel(const int* __restrict__ ei, int* __restrict__ flag){
  int z = (ei[1]==0) + (ei[3]==0) + (ei[5]==0) + (ei[7]==0);
  *flag = (z == 4) ? 1 : 0;
}

// ---------- fold W1 into Wkqv; emit TRANSPOSED bf16 WcombT[768][256] + fp32 bcomb[768] ----------
__global__ void prep_weights(const float* __restrict__ Wkqv, const float* __restrict__ bkqv,
                             const float* __restrict__ W1,
                             bf16_t* __restrict__ WcombT, float* __restrict__ bcomb){
  int n = blockIdx.x * blockDim.x + threadIdx.x;   // 0..767 (output col)
  int c = blockIdx.y;                              // 0..256 (k index; 256 = bias)
  if (n >= 768) return;
  const float rs = rsqrtf(128.0f);
  bool isBias = (c == 256);
  const float* arow = isBias ? bkqv : (Wkqv + (size_t)c*768);
  float val;
  if (n < 512){
    bool isQ = (n < 256);
    int nn = isQ ? n : (n - 256);
    int h = nn >> 7, d = nn & 127;
    int srcoff = isQ ? (h*128) : (256 + h*128);
    int w1off  = isQ ? 128 : 0;
    float s = 0.f;
    for (int t = 0; t < 128; ++t)
      s = fmaf(arow[srcoff + t], W1[(size_t)(w1off + t)*128 + d], s);
    val = isQ ? s : s * rs;
  } else {
    val = arow[512 + (n - 512)];
  }
  if (isBias) bcomb[n] = val;
  else        WcombT[(size_t)n*256 + c] = (bf16_t)val;
}

// ---------- Wout -> transposed bf16 WoutT[256][256] ----------
__global__ void prep_wout(const float* __restrict__ W, bf16_t* __restrict__ Wt){
  int t = blockIdx.x*blockDim.x + threadIdx.x;  // 65536
  int n = t & 255, c = t >> 8;
  Wt[(size_t)n*256 + c] = (bf16_t)W[(size_t)c*256 + n];
}

// ---------- degree count over the 2*E0 non-self edges (dst side) ----------
__global__ void deg_kernel(const int* __restrict__ ei, const int* __restrict__ flag,
                           int* __restrict__ deg, int E0, int Nn){
  int t = blockIdx.x*blockDim.x + threadIdx.x;
  if (t >= 2*E0) return;
  int is64 = *flag;
  int i = (t < E0) ? eidx(ei,is64,(long long)E0+t) : eidx(ei,is64,t-E0);
  i = min(max(i,0), Nn-1);
  atomicAdd(deg + i, 1);
}

// ---------- exclusive prefix scan of (deg+1) -> off[0..N] (self-loop slot included) ----------
__global__ __launch_bounds__(1024) void scan_kernel(const int* __restrict__ deg,
                                                    int* __restrict__ off, int N){
  __shared__ int wsum[16];
  __shared__ int carry_s;
  int tid = threadIdx.x, lane = tid & 63, w = tid >> 6;
  if (tid == 0) carry_s = 0;
  __syncthreads();
  for (int base = 0; base < N; base += 1024){
    int carry = carry_s;
    int v = (base + tid < N) ? (deg[base + tid] + 1) : 0;
    int incl = v;
    #pragma unroll
    for (int o = 1; o < 64; o <<= 1){
      int t = __shfl_up(incl, o, 64);
      if (lane >= o) incl += t;
    }
    if (lane == 63) wsum[w] = incl;
    __syncthreads();
    if (w == 0 && lane < 16){
      int sv = wsum[lane];
      #pragma unroll
      for (int o = 1; o < 16; o <<= 1){
        int t = __shfl_up(sv, o, 64);
        if (lane >= o) sv += t;
      }
      wsum[lane] = sv;
    }
    __syncthreads();
    int wpref = (w == 0) ? 0 : wsum[w-1];
    if (base + tid < N) off[base + tid] = carry + wpref + incl - v;
    __syncthreads();
    if (tid == 1023) carry_s = carry + wsum[15];
    __syncthreads();
  }
  if (threadIdx.x == 0) off[N] = carry_s;
}

// ---------- scatter source index j into CSR buckets (incl. self-loops) ----------
__global__ void scatter_kernel(const int* __restrict__ ei, const int* __restrict__ flag,
                               const int* __restrict__ off, int* __restrict__ cursor,
                               int* __restrict__ bj, int E0, int Nn){
  int e = blockIdx.x*blockDim.x + threadIdx.x;
  int E = 2*E0 + Nn;
  if (e >= E) return;
  int is64 = *flag;
  int j, i;
  if (e < E0){ j = eidx(ei,is64,e); i = eidx(ei,is64,(long long)E0+e); }
  else if (e < 2*E0){ int t = e - E0; i = eidx(ei,is64,t); j = eidx(ei,is64,(long long)E0+t); }
  else { i = j = e - 2*E0; }
  i = min(max(i,0), Nn-1); j = min(max(j,0), Nn-1);
  int pos = atomicAdd(cursor + i, 1);
  bj[off[i] + pos] = j;
}

// ---------- bf16 MFMA GEMM, K=256: C = A[M,256] @ Bt[N,256]^T + epilogue ----------
// R4 structure + (1) XCD swizzle: all n-tiles of an m-strip run on one XCD
// consecutively (A-strip fetched once into that XCD's L2); (2) single-barrier
// double-buffered K-loop (stage k+1 async right after barrier, compute k);
// (3) MODE0 stages A from fp32 x with in-kernel bf16 cvt (kills cvt_x pass);
// vmcnt wait for the fp32 prefetch lands AFTER the MFMAs (ds_write post-compute).
// MODE 0: A=fp32, C(bf16) = AB + bias[n]
// MODE 1: A=bf16 (async), C(fp32) = relu(AB + (deg[m]+1)*bias[n]) + xres[m*N+n]
template<int MODE, typename OutT>
__global__ __launch_bounds__(256) void mfma_gemm(
    const void* __restrict__ Av, const bf16_t* __restrict__ Bt,
    const float* __restrict__ bias, OutT* __restrict__ C,
    int M, int N,
    const int* __restrict__ deg, const float* __restrict__ xres)
{
  __shared__ bf16_t As[2][128*32];   // 8 KB each
  __shared__ bf16_t Bs[2][128*32];
  const int tid = threadIdx.x;
  const int wave = tid >> 6, lane = tid & 63;
  const int row16 = lane & 15, quad = lane >> 4;

  // XCD swizzle: bid%8 = XCD (dispatch round-robin heuristic); n fastest per XCD
  const int nn = N >> 7;
  const int bid = blockIdx.x;
  const int strip = bid / (8*nn);
  const int inner = bid % (8*nn);
  const int m0 = (strip*8 + (inner & 7)) * 128;
  const int n0 = (inner >> 3) * 128;
  const int wm = (wave >> 1) * 64, wn = (wave & 1) * 64;

  const float*  Af = (const float*)Av;
  const bf16_t* Ab = (const bf16_t*)Av;

  const int f0 = wave*2, f1 = wave*2 + 1;
  const int gm0 = min(m0 + f0*16 + row16, M-1);
  const int gm1 = min(m0 + f1*16 + row16, M-1);
  const int gn0 = n0 + f0*16 + row16;
  const int gn1 = n0 + f1*16 + row16;

  // ---- prologue: stage k-tile 0 into buffer 0
  if (MODE == 0){
    const float* g0 = Af + (size_t)gm0*256 + quad*8;
    const float* g1 = Af + (size_t)gm1*256 + quad*8;
    float4 a0 = *(const float4*)g0, a1 = *(const float4*)(g0+4);
    float4 c0 = *(const float4*)g1, c1 = *(const float4*)(g1+4);
    bf16x8 v0 = {(bf16_t)a0.x,(bf16_t)a0.y,(bf16_t)a0.z,(bf16_t)a0.w,
                 (bf16_t)a1.x,(bf16_t)a1.y,(bf16_t)a1.z,(bf16_t)a1.w};
    bf16x8 v1 = {(bf16_t)c0.x,(bf16_t)c0.y,(bf16_t)c0.z,(bf16_t)c0.w,
                 (bf16_t)c1.x,(bf16_t)c1.y,(bf16_t)c1.z,(bf16_t)c1.w};
    *(bf16x8*)((char*)As[0] + f0*1024 + lane*16) = v0;
    *(bf16x8*)((char*)As[0] + f1*1024 + lane*16) = v1;
  } else {
    async_load16(Ab + (size_t)gm0*256 + quad*8, (char*)As[0] + f0*1024);
    async_load16(Ab + (size_t)gm1*256 + quad*8, (char*)As[0] + f1*1024);
  }
  async_load16(Bt + (size_t)gn0*256 + quad*8, (char*)Bs[0] + f0*1024);
  async_load16(Bt + (size_t)gn1*256 + quad*8, (char*)Bs[0] + f1*1024);

  floatx4 acc[4][4];
  #pragma unroll
  for (int a=0;a<4;++a)
    #pragma unroll
    for (int b=0;b<4;++b) acc[a][b] = (floatx4){0.f,0.f,0.f,0.f};

  #pragma unroll
  for (int kt = 0; kt < 8; ++kt){
    const int cur = kt & 1, nxt = cur ^ 1;
    const int k1 = (kt+1)*32;
    const bool pre = (kt < 7);
    float4 p0, p1, p2, p3;

    __syncthreads();   // buffer[cur] staged (vmcnt/lgkm drained here) & buffer[nxt] free

    if (pre){
      if (MODE == 0){
        const float* g0 = Af + (size_t)gm0*256 + k1 + quad*8;
        const float* g1 = Af + (size_t)gm1*256 + k1 + quad*8;
        p0 = *(const float4*)g0; p1 = *(const float4*)(g0+4);
        p2 = *(const float4*)g1; p3 = *(const float4*)(g1+4);
      } else {
        async_load16(Ab + (size_t)gm0*256 + k1 + quad*8, (char*)As[nxt] + f0*1024);
        async_load16(Ab + (size_t)gm1*256 + k1 + quad*8, (char*)As[nxt] + f1*1024);
      }
      async_load16(Bt + (size_t)gn0*256 + k1 + quad*8, (char*)Bs[nxt] + f0*1024);
      async_load16(Bt + (size_t)gn1*256 + k1 + quad*8, (char*)Bs[nxt] + f1*1024);
    }

    bf16x8 af[4], bfr[4];
    #pragma unroll
    for (int t = 0; t < 4; ++t){
      af[t]  = *(const bf16x8*)((const char*)As[cur] + ((wm>>4)+t)*1024 + lane*16);
      bfr[t] = *(const bf16x8*)((const char*)Bs[cur] + ((wn>>4)+t)*1024 + lane*16);
    }
    #pragma unroll
    for (int mt=0;mt<4;++mt)
      #pragma unroll
      for (int nt=0;nt<4;++nt)
        acc[mt][nt] = __builtin_amdgcn_mfma_f32_16x16x32_bf16(af[mt], bfr[nt], acc[mt][nt], 0,0,0);

    if (pre && MODE == 0){   // cvt+write AFTER compute: fp32 loads had MFMA phase to land
      bf16x8 v0 = {(bf16_t)p0.x,(bf16_t)p0.y,(bf16_t)p0.z,(bf16_t)p0.w,
                   (bf16_t)p1.x,(bf16_t)p1.y,(bf16_t)p1.z,(bf16_t)p1.w};
      bf16x8 v1 = {(bf16_t)p2.x,(bf16_t)p2.y,(bf16_t)p2.z,(bf16_t)p2.w,
                   (bf16_t)p3.x,(bf16_t)p3.y,(bf16_t)p3.z,(bf16_t)p3.w};
      *(bf16x8*)((char*)As[nxt] + f0*1024 + lane*16) = v0;
      *(bf16x8*)((char*)As[nxt] + f1*1024 + lane*16) = v1;
    }
  }

  // epilogue: C/D layout col=lane&15, row=quad*4+reg
  #pragma unroll
  for (int mt=0;mt<4;++mt){
    #pragma unroll
    for (int r=0;r<4;++r){
      int m = m0 + wm + mt*16 + quad*4 + r;
      if (m >= M) continue;
      float dg = (MODE==1) ? (float)(deg[m]+1) : 0.f;
      #pragma unroll
      for (int nt=0;nt<4;++nt){
        int n = n0 + wn + nt*16 + row16;
        float v = acc[mt][nt][r];
        if (MODE == 0){
          v += bias[n];
        } else {
          v = fmaxf(v + dg*bias[n], 0.f) + xres[(size_t)m*N + n];
        }
        C[(size_t)m*N + n] = (OutT)v;
      }
    }
  }
}

// ---------- fused attention: score + online softmax + aggregate, one wave per node ----------
__global__ __launch_bounds__(256) void fused_attn_kernel(
    const bf16_t* __restrict__ P, const int* __restrict__ bj, const int* __restrict__ off,
    const float* __restrict__ b1, const float* __restrict__ W2, const float* __restrict__ b2,
    bf16_t* __restrict__ aggb, int Nn)
{
  int i = blockIdx.x * (blockDim.x >> 6) + (threadIdx.x >> 6);
  if (i >= Nn) return;
  int lane = threadIdx.x & 63;
  int h = lane >> 5, d = (lane & 31) * 4;

  const float4 qv  = cvt4(*(const bf16x4*)(P + (size_t)i*768 + h*128 + d));
  const float4 b1v = *(const float4*)(b1 + d);
  const float4 w2v = *(const float4*)(W2 + d);
  const float b2v  = b2[0];

  float m = -3.0e38f, s = 0.f;
  float4 acc = make_float4(0.f,0.f,0.f,0.f);
  int s0 = off[i], s1 = off[i+1];
  for (int t = s0; t < s1; ++t){
    int j = bj[t];
    const float4 kv = cvt4(*(const bf16x4*)(P + (size_t)j*768 + 256 + h*128 + d));
    const float4 vv = cvt4(*(const bf16x4*)(P + (size_t)j*768 + 512 + h*128 + d));
    float p = fmaxf(qv.x+kv.x+b1v.x, 0.f)*w2v.x
            + fmaxf(qv.y+kv.y+b1v.y, 0.f)*w2v.y
            + fmaxf(qv.z+kv.z+b1v.z, 0.f)*w2v.z
            + fmaxf(qv.w+kv.w+b1v.w, 0.f)*w2v.w;
    #pragma unroll
    for (int o = 16; o >= 1; o >>= 1)
      p += __shfl_xor(p, o, 64);
    float a = p + b2v;
    float mn = fmaxf(m, a);
    float sc = __expf(m - mn);
    float e  = __expf(a - mn);
    s = s*sc + e;
    acc.x = fmaf(acc.x, sc, e*vv.x);
    acc.y = fmaf(acc.y, sc, e*vv.y);
    acc.z = fmaf(acc.z, sc, e*vv.z);
    acc.w = fmaf(acc.w, sc, e*vv.w);
    m = mn;
  }
  float inv = 1.f / (s + 1e-16f);
  bf16x4 ob = { (bf16_t)(acc.x*inv), (bf16_t)(acc.y*inv), (bf16_t)(acc.z*inv), (bf16_t)(acc.w*inv) };
  *(bf16x4*)(aggb + (size_t)i*256 + h*128 + d) = ob;
}

// ---------- launch ----------
extern "C" void kernel_launch(void* const* d_in, const int* in_sizes, int n_in,
                              void* d_out, int out_size, void* d_ws, size_t ws_size,
                              hipStream_t stream)
{
  const float* x     = (const float*)d_in[0];
  const int*   ei    = (const int*)d_in[1];
  const float* Wkqv  = (const float*)d_in[2];
  const float* bkqv  = (const float*)d_in[3];
  const float* W1    = (const float*)d_in[4];
  const float* b1    = (const float*)d_in[5];
  const float* W2    = (const float*)d_in[6];
  const float* b2    = (const float*)d_in[7];
  const float* Wout  = (const float*)d_in[8];
  const float* bout  = (const float*)d_in[9];
  float* out = (float*)d_out;

  const int N  = in_sizes[0] / EMB;   // 50000
  const int E0 = in_sizes[1] / 2;     // 100000
  const int E  = 2*E0 + N;            // 250000

  // workspace layout (fp32-word offsets; all 16B-aligned)
  float* base = (float*)d_ws;
  bf16_t* WcombT = (bf16_t*)base;                       // 768*256 bf16
  float*  bcomb  = base + 98304;                        // 768 w
  bf16_t* WoutT  = (bf16_t*)(base + 98304 + 768);       // 256*256 bf16
  bf16_t* Pb     = (bf16_t*)(base + 131840);            // N*768 bf16
  bf16_t* aggb   = (bf16_t*)(Pb + (size_t)N*768);       // N*256 bf16
  int* deg       = (int*)(aggb + (size_t)N*256);        // N
  int* cursor    = deg + N;                             // N
  int* flag      = cursor + N;                          // 1
  int* off       = flag + 1;                            // N+1
  int* bj        = off + (N+1);                         // E

  hipMemsetAsync(deg, 0, (size_t)2*N*sizeof(int), stream);  // deg + cursor

  detect_kernel<<<1,1,0,stream>>>(ei, flag);
  prep_weights<<<dim3(3,257),256,0,stream>>>(Wkqv, bkqv, W1, WcombT, bcomb);
  prep_wout<<<256,256,0,stream>>>(Wout, WoutT);

  deg_kernel<<<(2*E0+255)/256,256,0,stream>>>(ei, flag, deg, E0, N);
  scan_kernel<<<1,1024,0,stream>>>(deg, off, N);
  scatter_kernel<<<(E+255)/256,256,0,stream>>>(ei, flag, off, cursor, bj, E0, N);

  const int nm8 = (((N+127)/128) + 7) & ~7;   // m-strips padded to multiple of 8
  mfma_gemm<0, bf16_t><<<nm8*6,256,0,stream>>>(x, WcombT, bcomb, Pb, N, 768, nullptr, nullptr);
  fused_attn_kernel<<<(N+3)/4,256,0,stream>>>(Pb, bj, off, b1, W2, b2, aggb, N);
  mfma_gemm<1, float><<<nm8*2,256,0,stream>>>(aggb, WoutT, bout, out, N, 256, deg, x);
}

// Round 7
// 336.302 us; speedup vs baseline: 1.1584x; 1.0253x over previous
//
#include <hip/hip_runtime.h>
#include <hip/hip_bf16.h>

#define EMB 256

typedef __bf16 bf16_t;
typedef __attribute__((ext_vector_type(8))) __bf16 bf16x8;
typedef __attribute__((ext_vector_type(4))) __bf16 bf16x4;
typedef __attribute__((ext_vector_type(4))) float floatx4;

// ---------- helpers ----------
__device__ __forceinline__ int eidx(const int* __restrict__ p, int is64, long long k){
  return is64 ? p[2*k] : p[(int)k];
}
// async global->LDS, 16B per lane; LDS base must be WAVE-UNIFORM, lands at base + lane*16
__device__ __forceinline__ void async_load16(const void* g, void* l){
  __builtin_amdgcn_global_load_lds(
      (const __attribute__((address_space(1))) unsigned int*)g,
      (__attribute__((address_space(3))) unsigned int*)l,
      16, 0, 0);
}
__device__ __forceinline__ float4 cvt4(bf16x4 v){
  return make_float4((float)v.x, (float)v.y, (float)v.z, (float)v.w);
}

// ---------- dtype detect ----------
__global__ void detect_kernel(const int* __restrict__ ei, int* __restrict__ flag){
  int z = (ei[1]==0) + (ei[3]==0) + (ei[5]==0) + (ei[7]==0);
  *flag = (z == 4) ? 1 : 0;
}

// ---------- x -> bf16 ----------
__global__ void cvt_x_kernel(const float* __restrict__ x, bf16_t* __restrict__ xb, int n4){
  int t = blockIdx.x*blockDim.x + threadIdx.x;
  if (t >= n4) return;
  const float4 v = *(const float4*)(x + (size_t)t*4);
  bf16x4 o = { (bf16_t)v.x, (bf16_t)v.y, (bf16_t)v.z, (bf16_t)v.w };
  *(bf16x4*)(xb + (size_t)t*4) = o;
}

// ---------- fold W1 into Wkqv; emit TRANSPOSED bf16 WcombT[768][256] + fp32 bcomb[768] ----------
// Output column layout (KV-PACKED): cols [0,256) = q (h*128+d);
// cols [256,768): r = n-256, h = r>>8, g = (r&255)>>3, half = (r>>2)&1, dd = r&3, d = g*4+dd;
//   half 0 -> k_scaled[h][d], half 1 -> v[h][d].
// So per (head, 4-dim group): 4 k elems then 4 v elems adjacent -> one bf16x8 load in attn.
__global__ void prep_weights(const float* __restrict__ Wkqv, const float* __restrict__ bkqv,
                             const float* __restrict__ W1,
                             bf16_t* __restrict__ WcombT, float* __restrict__ bcomb){
  int n = blockIdx.x * blockDim.x + threadIdx.x;   // 0..767 (output col, permuted layout)
  int c = blockIdx.y;                              // 0..256 (k index; 256 = bias)
  if (n >= 768) return;
  const float rs = rsqrtf(128.0f);
  bool isBias = (c == 256);
  const float* arow = isBias ? bkqv : (Wkqv + (size_t)c*768);
  float val;
  if (n < 256){                       // q
    int h = n >> 7, d = n & 127;
    float s = 0.f;
    for (int t = 0; t < 128; ++t)
      s = fmaf(arow[h*128 + t], W1[(size_t)(128 + t)*128 + d], s);
    val = s;
  } else {
    int r = n - 256;
    int h = r >> 8, t8 = r & 255;
    int g = t8 >> 3, half = (t8 >> 2) & 1, dd = t8 & 3;
    int d = g*4 + dd;
    if (half == 0){                   // k (scaled)
      float s = 0.f;
      for (int t = 0; t < 128; ++t)
        s = fmaf(arow[256 + h*128 + t], W1[(size_t)t*128 + d], s);
      val = s * rs;
    } else {                          // v passthrough
      val = arow[512 + h*128 + d];
    }
  }
  if (isBias) bcomb[n] = val;
  else        WcombT[(size_t)n*256 + c] = (bf16_t)val;
}

// ---------- Wout -> transposed bf16 WoutT[256][256] ----------
__global__ void prep_wout(const float* __restrict__ W, bf16_t* __restrict__ Wt){
  int t = blockIdx.x*blockDim.x + threadIdx.x;  // 65536
  int n = t & 255, c = t >> 8;
  Wt[(size_t)n*256 + c] = (bf16_t)W[(size_t)c*256 + n];
}

// ---------- degree count over the 2*E0 non-self edges (dst side) ----------
__global__ void deg_kernel(const int* __restrict__ ei, const int* __restrict__ flag,
                           int* __restrict__ deg, int E0, int Nn){
  int t = blockIdx.x*blockDim.x + threadIdx.x;
  if (t >= 2*E0) return;
  int is64 = *flag;
  int i = (t < E0) ? eidx(ei,is64,(long long)E0+t) : eidx(ei,is64,t-E0);
  i = min(max(i,0), Nn-1);
  atomicAdd(deg + i, 1);
}

// ---------- exclusive prefix scan of (deg+1) -> off[0..N] (self-loop slot included) ----------
__global__ __launch_bounds__(1024) void scan_kernel(const int* __restrict__ deg,
                                                    int* __restrict__ off, int N){
  __shared__ int wsum[16];
  __shared__ int carry_s;
  int tid = threadIdx.x, lane = tid & 63, w = tid >> 6;
  if (tid == 0) carry_s = 0;
  __syncthreads();
  for (int base = 0; base < N; base += 1024){
    int carry = carry_s;
    int v = (base + tid < N) ? (deg[base + tid] + 1) : 0;
    int incl = v;
    #pragma unroll
    for (int o = 1; o < 64; o <<= 1){
      int t = __shfl_up(incl, o, 64);
      if (lane >= o) incl += t;
    }
    if (lane == 63) wsum[w] = incl;
    __syncthreads();
    if (w == 0 && lane < 16){
      int sv = wsum[lane];
      #pragma unroll
      for (int o = 1; o < 16; o <<= 1){
        int t = __shfl_up(sv, o, 64);
        if (lane >= o) sv += t;
      }
      wsum[lane] = sv;
    }
    __syncthreads();
    int wpref = (w == 0) ? 0 : wsum[w-1];
    if (base + tid < N) off[base + tid] = carry + wpref + incl - v;
    __syncthreads();
    if (tid == 1023) carry_s = carry + wsum[15];
    __syncthreads();
  }
  if (threadIdx.x == 0) off[N] = carry_s;
}

// ---------- scatter source index j into CSR buckets (incl. self-loops) ----------
__global__ void scatter_kernel(const int* __restrict__ ei, const int* __restrict__ flag,
                               const int* __restrict__ off, int* __restrict__ cursor,
                               int* __restrict__ bj, int E0, int Nn){
  int e = blockIdx.x*blockDim.x + threadIdx.x;
  int E = 2*E0 + Nn;
  if (e >= E) return;
  int is64 = *flag;
  int j, i;
  if (e < E0){ j = eidx(ei,is64,e); i = eidx(ei,is64,(long long)E0+e); }
  else if (e < 2*E0){ int t = e - E0; i = eidx(ei,is64,t); j = eidx(ei,is64,(long long)E0+t); }
  else { i = j = e - 2*E0; }
  i = min(max(i,0), Nn-1); j = min(max(j,0), Nn-1);
  int pos = atomicAdd(cursor + i, 1);
  bj[off[i] + pos] = j;
}

// ---------- bf16 MFMA GEMM, K=256: C = A[M,256] @ Bt[N,256]^T + epilogue ----------
// All-async staging (global_load_lds w16, fragment-ordered LDS), double-buffered
// single-barrier K-loop, XCD swizzle (n-tiles of an m-strip stay on one XCD).
// MODE 0: C(bf16) = AB + bias[n]
// MODE 1: C(fp32) = relu(AB + (deg[m]+1)*bias[n]) + xres[m*N+n]
template<int MODE, typename OutT>
__global__ __launch_bounds__(256) void mfma_gemm(
    const bf16_t* __restrict__ A, const bf16_t* __restrict__ Bt,
    const float* __restrict__ bias, OutT* __restrict__ C,
    int M, int N,
    const int* __restrict__ deg, const float* __restrict__ xres)
{
  __shared__ bf16_t As[2][128*32];   // 8 KB each
  __shared__ bf16_t Bs[2][128*32];
  const int tid = threadIdx.x;
  const int wave = tid >> 6, lane = tid & 63;
  const int row16 = lane & 15, quad = lane >> 4;

  // XCD swizzle: bid%8 = XCD (dispatch round-robin heuristic); n fastest per XCD
  const int nn = N >> 7;
  const int bid = blockIdx.x;
  const int strip = bid / (8*nn);
  const int inner = bid % (8*nn);
  const int m0 = (strip*8 + (inner & 7)) * 128;
  const int n0 = (inner >> 3) * 128;
  const int wm = (wave >> 1) * 64, wn = (wave & 1) * 64;

  const int f0 = wave*2, f1 = wave*2 + 1;
  const int gm0 = min(m0 + f0*16 + row16, M-1);
  const int gm1 = min(m0 + f1*16 + row16, M-1);
  const int gn0 = n0 + f0*16 + row16;
  const int gn1 = n0 + f1*16 + row16;

  // prologue: stage k-tile 0 into buffer 0
  async_load16(A  + (size_t)gm0*256 + quad*8, (char*)As[0] + f0*1024);
  async_load16(A  + (size_t)gm1*256 + quad*8, (char*)As[0] + f1*1024);
  async_load16(Bt + (size_t)gn0*256 + quad*8, (char*)Bs[0] + f0*1024);
  async_load16(Bt + (size_t)gn1*256 + quad*8, (char*)Bs[0] + f1*1024);

  floatx4 acc[4][4];
  #pragma unroll
  for (int a=0;a<4;++a)
    #pragma unroll
    for (int b=0;b<4;++b) acc[a][b] = (floatx4){0.f,0.f,0.f,0.f};

  #pragma unroll
  for (int kt = 0; kt < 8; ++kt){
    const int cur = kt & 1, nxt = cur ^ 1;
    const int k1 = (kt+1)*32;

    __syncthreads();   // buffer[cur] staged; buffer[nxt] free

    if (kt < 7){
      async_load16(A  + (size_t)gm0*256 + k1 + quad*8, (char*)As[nxt] + f0*1024);
      async_load16(A  + (size_t)gm1*256 + k1 + quad*8, (char*)As[nxt] + f1*1024);
      async_load16(Bt + (size_t)gn0*256 + k1 + quad*8, (char*)Bs[nxt] + f0*1024);
      async_load16(Bt + (size_t)gn1*256 + k1 + quad*8, (char*)Bs[nxt] + f1*1024);
    }

    bf16x8 af[4], bfr[4];
    #pragma unroll
    for (int t = 0; t < 4; ++t){
      af[t]  = *(const bf16x8*)((const char*)As[cur] + ((wm>>4)+t)*1024 + lane*16);
      bfr[t] = *(const bf16x8*)((const char*)Bs[cur] + ((wn>>4)+t)*1024 + lane*16);
    }
    #pragma unroll
    for (int mt=0;mt<4;++mt)
      #pragma unroll
      for (int nt=0;nt<4;++nt)
        acc[mt][nt] = __builtin_amdgcn_mfma_f32_16x16x32_bf16(af[mt], bfr[nt], acc[mt][nt], 0,0,0);
  }

  // epilogue: C/D layout col=lane&15, row=quad*4+reg
  #pragma unroll
  for (int mt=0;mt<4;++mt){
    #pragma unroll
    for (int r=0;r<4;++r){
      int m = m0 + wm + mt*16 + quad*4 + r;
      if (m >= M) continue;
      float dg = (MODE==1) ? (float)(deg[m]+1) : 0.f;
      #pragma unroll
      for (int nt=0;nt<4;++nt){
        int n = n0 + wn + nt*16 + row16;
        float v = acc[mt][nt][r];
        if (MODE == 0){
          v += bias[n];
        } else {
          v = fmaxf(v + dg*bias[n], 0.f) + xres[(size_t)m*N + n];
        }
        C[(size_t)m*N + n] = (OutT)v;
      }
    }
  }
}

// ---------- fused attention: score + online softmax + aggregate, one wave per node ----------
// P layout: [0,256) q; [256,768) kv-packed: head h at 256+h*256, group g holds
// k[g*4..g*4+3] then v[g*4..g*4+3] -> ONE bf16x8 load per edge per lane.
__global__ __launch_bounds__(256) void fused_attn_kernel(
    const bf16_t* __restrict__ P, const int* __restrict__ bj, const int* __restrict__ off,
    const float* __restrict__ b1, const float* __restrict__ W2, const float* __restrict__ b2,
    bf16_t* __restrict__ aggb, int Nn)
{
  int i = blockIdx.x * (blockDim.x >> 6) + (threadIdx.x >> 6);
  if (i >= Nn) return;
  int lane = threadIdx.x & 63;
  int h = lane >> 5, g = lane & 31, d = g * 4;

  const float4 qv  = cvt4(*(const bf16x4*)(P + (size_t)i*768 + h*128 + d));
  const float4 b1v = *(const float4*)(b1 + d);
  const float4 w2v = *(const float4*)(W2 + d);
  const float b2v  = b2[0];

  float m = -3.0e38f, s = 0.f;
  float4 acc = make_float4(0.f,0.f,0.f,0.f);
  int s0 = off[i], s1 = off[i+1];
  for (int t = s0; t < s1; ++t){
    int j = bj[t];
    bf16x8 kvv = *(const bf16x8*)(P + (size_t)j*768 + 256 + h*256 + g*8);
    float kx = (float)kvv[0], ky = (float)kvv[1], kz = (float)kvv[2], kw = (float)kvv[3];
    float vx = (float)kvv[4], vy = (float)kvv[5], vz = (float)kvv[6], vw = (float)kvv[7];
    float p = fmaxf(qv.x+kx+b1v.x, 0.f)*w2v.x
            + fmaxf(qv.y+ky+b1v.y, 0.f)*w2v.y
            + fmaxf(qv.z+kz+b1v.z, 0.f)*w2v.z
            + fmaxf(qv.w+kw+b1v.w, 0.f)*w2v.w;
    // reduce across the 32-lane half-wave (bit5 = head, untouched)
    #pragma unroll
    for (int o = 16; o >= 1; o >>= 1)
      p += __shfl_xor(p, o, 64);
    float a = p + b2v;
    float mn = fmaxf(m, a);
    float sc = __expf(m - mn);
    float e  = __expf(a - mn);
    s = s*sc + e;
    acc.x = fmaf(acc.x, sc, e*vx);
    acc.y = fmaf(acc.y, sc, e*vy);
    acc.z = fmaf(acc.z, sc, e*vz);
    acc.w = fmaf(acc.w, sc, e*vw);
    m = mn;
  }
  float inv = 1.f / (s + 1e-16f);
  bf16x4 ob = { (bf16_t)(acc.x*inv), (bf16_t)(acc.y*inv), (bf16_t)(acc.z*inv), (bf16_t)(acc.w*inv) };
  *(bf16x4*)(aggb + (size_t)i*256 + h*128 + d) = ob;
}

// ---------- launch ----------
extern "C" void kernel_launch(void* const* d_in, const int* in_sizes, int n_in,
                              void* d_out, int out_size, void* d_ws, size_t ws_size,
                              hipStream_t stream)
{
  const float* x     = (const float*)d_in[0];
  const int*   ei    = (const int*)d_in[1];
  const float* Wkqv  = (const float*)d_in[2];
  const float* bkqv  = (const float*)d_in[3];
  const float* W1    = (const float*)d_in[4];
  const float* b1    = (const float*)d_in[5];
  const float* W2    = (const float*)d_in[6];
  const float* b2    = (const float*)d_in[7];
  const float* Wout  = (const float*)d_in[8];
  const float* bout  = (const float*)d_in[9];
  float* out = (float*)d_out;

  const int N  = in_sizes[0] / EMB;   // 50000
  const int E0 = in_sizes[1] / 2;     // 100000
  const int E  = 2*E0 + N;            // 250000

  // workspace layout (fp32-word offsets; all 16B-aligned)
  float* base = (float*)d_ws;
  bf16_t* WcombT = (bf16_t*)base;                       // 768*256 bf16
  float*  bcomb  = base + 98304;                        // 768 w
  bf16_t* WoutT  = (bf16_t*)(base + 98304 + 768);       // 256*256 bf16
  bf16_t* xb     = (bf16_t*)(base + 131840);            // N*256 bf16
  bf16_t* Pb     = (bf16_t*)(base + 131840 + 6400000);  // N*768 bf16
  bf16_t* aggb   = (bf16_t*)(Pb + (size_t)N*768);       // N*256 bf16
  int* deg       = (int*)(aggb + (size_t)N*256);        // N
  int* cursor    = deg + N;                             // N
  int* flag      = cursor + N;                          // 1
  int* off       = flag + 1;                            // N+1
  int* bj        = off + (N+1);                         // E

  hipMemsetAsync(deg, 0, (size_t)2*N*sizeof(int), stream);  // deg + cursor

  detect_kernel<<<1,1,0,stream>>>(ei, flag);
  cvt_x_kernel<<<((N*EMB/4)+255)/256,256,0,stream>>>(x, xb, N*EMB/4);
  prep_weights<<<dim3(3,257),256,0,stream>>>(Wkqv, bkqv, W1, WcombT, bcomb);
  prep_wout<<<256,256,0,stream>>>(Wout, WoutT);

  deg_kernel<<<(2*E0+255)/256,256,0,stream>>>(ei, flag, deg, E0, N);
  scan_kernel<<<1,1024,0,stream>>>(deg, off, N);
  scatter_kernel<<<(E+255)/256,256,0,stream>>>(ei, flag, off, cursor, bj, E0, N);

  const int nm8 = (((N+127)/128) + 7) & ~7;   // m-strips padded to multiple of 8
  mfma_gemm<0, bf16_t><<<nm8*6,256,0,stream>>>(xb, WcombT, bcomb, Pb, N, 768, nullptr, nullptr);
  fused_attn_kernel<<<(N+3)/4,256,0,stream>>>(Pb, bj, off, b1, W2, b2, aggb, N);
  mfma_gemm<1, float><<<nm8*2,256,0,stream>>>(aggb, WoutT, bout, out, N, 256, deg, x);
}